// Round 2
// baseline (2939.102 us; speedup 1.0000x reference)
//
#include <hip/hip_runtime.h>
#include <math.h>

#define Tt 4096
#define NB 16

#define CLN2PI 1.8378770664093453f   // ln(2*pi)

// ws layout (float offsets)
#define OFF_W    0         // 131072  W = L^-1 per state (row-major, upper zeros)
#define OFF_D    131072    // 2048    d = W*mu
#define OFF_CST  133120    // 32      F*ln2pi + logdet  (nats)
#define OFF_EV   133152    // 16      evidence per batch (fp32 nats)
#define OFF_LB   133184    // 2097152 logB nats [b][t][s]
#define OFF_BET  2230336   // 2097152 beta  nats [b][t][s]
// total 4327488 floats = 17.3 MB

__device__ __forceinline__ float rdlane(float x, int l) {
  return __int_as_float(__builtin_amdgcn_readlane(__float_as_int(x), l));
}

// ---------------- K2: per-state Cholesky, W = L^-1, d = W*mu, cst ----------------
__global__ __launch_bounds__(64) void k_chol(const float* __restrict__ covs,
                                             const float* __restrict__ means,
                                             float* __restrict__ ws) {
  __shared__ float Am[64][65];
  __shared__ float Wl[64][65];
  int s = blockIdx.x, j = threadIdx.x;
  for (int r = 0; r < 64; ++r) {
    Am[r][j] = covs[((size_t)s * 64 + r) * 64 + j];
    Wl[r][j] = 0.f;
  }
  __syncthreads();
  for (int k = 0; k < 64; ++k) {
    float diag = sqrtf(Am[k][k]);
    float col = (j > k) ? Am[j][k] / diag : 0.f;
    __syncthreads();
    if (j == k) Am[k][k] = diag;
    if (j > k)  Am[j][k] = col;
    __syncthreads();
    if (j > k) {
      for (int g = k + 1; g <= j; ++g) Am[j][g] -= col * Am[g][k];
    }
    __syncthreads();
  }
  {
    int c = j;
    Wl[c][c] = 1.0f / Am[c][c];
    for (int f = c + 1; f < 64; ++f) {
      float ssum = 0.f;
      for (int g = c; g < f; ++g) ssum += Am[f][g] * Wl[g][c];
      Wl[f][c] = -ssum / Am[f][f];
    }
  }
  __syncthreads();
  for (int r = 0; r < 64; ++r)
    ws[OFF_W + ((size_t)s * 64 + r) * 64 + j] = Wl[r][j];
  {
    float acc = 0.f;
    for (int g = 0; g < 64; ++g) acc += Wl[j][g] * means[s * 64 + g];
    ws[OFF_D + s * 64 + j] = acc;
  }
  if (j == 0) {
    float logdet = 0.f;
    for (int k = 0; k < 64; ++k) logdet += __logf(Am[k][k]);
    logdet *= 2.0f;
    ws[OFF_CST + s] = 64.0f * CLN2PI + logdet;
  }
}

// ---------------- K3: emission logB (nats) ----------------
__global__ __launch_bounds__(64) void k_emis(const float* __restrict__ x,
                                             const float* __restrict__ wsr,
                                             float* __restrict__ lb) {
  const float* W = wsr + OFF_W;
  const float* D = wsr + OFF_D;
  const float* C = wsr + OFF_CST;
  int bx = blockIdx.x;
  int sgrp = bx & 3;
  int pt = (bx >> 2) * 64 + threadIdx.x;
  const float* xr = x + (size_t)pt * 64;
  float xv[64];
#pragma unroll
  for (int c = 0; c < 16; ++c) {
    float4 q = ((const float4*)xr)[c];
    xv[4 * c + 0] = q.x; xv[4 * c + 1] = q.y;
    xv[4 * c + 2] = q.z; xv[4 * c + 3] = q.w;
  }
#pragma unroll 1
  for (int si = 0; si < 8; ++si) {
    int s = sgrp * 8 + si;
    const float* Ws = W + (size_t)s * 4096;
    const float* Ds = D + s * 64;
    float maha = 0.f;
#pragma unroll
    for (int f = 0; f < 64; ++f) {
      float z = -Ds[f];
#pragma unroll
      for (int ch = 0; ch < 4; ++ch) {
        if (ch <= (f >> 4)) {
#pragma unroll
          for (int gg = 0; gg < 16; ++gg) {
            int g = ch * 16 + gg;
            z = fmaf(Ws[f * 64 + g], xv[g], z);
          }
        }
      }
      maha = fmaf(z, z, maha);
    }
    lb[(size_t)pt * 32 + s] = -0.5f * (maha + C[s]);
  }
}

// np-pairwise-order sum of 32 (matches numpy's 8-accumulator pairwise order)
__device__ __forceinline__ float npsum32(const float* z) {
  float r[8];
#pragma unroll
  for (int k = 0; k < 8; ++k)
    r[k] = ((z[k] + z[k + 8]) + z[k + 16]) + z[k + 24];
  return ((r[0] + r[1]) + (r[2] + r[3])) + ((r[4] + r[5]) + (r[6] + r[7]));
}
// exact max of 32 (order-independent, commutative -> any tree ok)
__device__ __forceinline__ float max32(const float* z) {
  float t16[16];
#pragma unroll
  for (int k = 0; k < 16; ++k) t16[k] = fmaxf(z[k], z[k + 16]);
  float t8[8];
#pragma unroll
  for (int k = 0; k < 8; ++k) t8[k] = fmaxf(t16[k], t16[k + 8]);
  float t4[4];
#pragma unroll
  for (int k = 0; k < 4; ++k) t4[k] = fmaxf(t8[k], t8[k + 4]);
  float t2a = fmaxf(t4[0], t4[2]), t2b = fmaxf(t4[1], t4[3]);
  return fmaxf(t2a, t2b);
}

// ---------------- K4: forward/backward, fp32 nats, np-matched ops ----------------
// 1 wave per (batch, dir). lane j (&31) owns state j; halves duplicate.
// R1 lesson: the np reference's big-magnitude fp32 rounding walk (~1.7 nats at
// t~4096) means ONLY an np-op-order-matched serial chain stays within threshold.
// R3/R0 lesson: VGPR_Count=40 in counters -> z[32] was REMATERIALIZED every use
// (register starvation; acol pins ate the budget). Pin z after creation and
// after exp so compiler allocates ~96+ VGPRs and computes each value once.
// Arithmetic is bit-identical to the passing R0 kernel.
__global__ __launch_bounds__(64, 1) __attribute__((amdgpu_waves_per_eu(1, 1)))
void k_fb(const float* __restrict__ logA,
          const float* __restrict__ logpi,
          float* __restrict__ ws,
          float* __restrict__ out) {
  const float* lbg = ws + OFF_LB;
  float* bet = ws + OFF_BET;
  float* ev  = ws + OFF_EV;
  int chain = blockIdx.x;
  int b   = chain & 15;
  int dir = chain >> 4;
  int lane = threadIdx.x;
  int j = lane & 31;
  const float* lb = lbg + (size_t)b * Tt * 32;
  if (dir == 0) {
    float acol[32];                      // A[i][j] for all i — keep in VGPRs
#pragma unroll
    for (int i = 0; i < 32; ++i) {
      acol[i] = logA[i * 32 + j];
      asm volatile("" : "+v"(acol[i]));  // pin: no remat from memory
    }
    float* ao = out + (size_t)b * Tt * 32;
    float a = logpi[j] + lb[j];          // alpha[0]
    ao[j] = a;
    float bA = lb[32 + j];
    float bB = lb[64 + j];
    float bC = lb[96 + j];
#pragma unroll 1
    for (int t = 1; t < Tt; ++t) {
      float bcur = bA; bA = bB; bB = bC;
      if (t + 3 < Tt) bC = lb[(size_t)(t + 3) * 32 + j];
      float z[32];
#pragma unroll
      for (int i = 0; i < 32; ++i) z[i] = rdlane(a, i) + acol[i];  // a_i + A[i][j]
#pragma unroll
      for (int i = 0; i < 32; ++i) asm volatile("" : "+v"(z[i])); // force z resident
      float m = max32(z);
#pragma unroll
      for (int i = 0; i < 32; ++i) z[i] = __expf(z[i] - m);        // exact sub
#pragma unroll
      for (int i = 0; i < 32; ++i) asm volatile("" : "+v"(z[i])); // force e resident
      float S = npsum32(z);
      a = (__logf(S) + m) + bcur;        // ((log S + max) + logB[t]) as in ref
      ao[(size_t)t * 32 + j] = a;        // halves write same value -> safe
    }
    // evidence = logsumexp(alpha[T-1])
    float z[32];
#pragma unroll
    for (int i = 0; i < 32; ++i) z[i] = rdlane(a, i);
    float m = max32(z);
#pragma unroll
    for (int i = 0; i < 32; ++i) z[i] = __expf(z[i] - m);
    float S = npsum32(z);
    if (lane == 0) ev[b] = __logf(S) + m;
  } else {
    float arow[32];                      // A[j][i] for all i — keep in VGPRs
#pragma unroll
    for (int i = 0; i < 32; ++i) {
      arow[i] = logA[j * 32 + i];
      asm volatile("" : "+v"(arow[i]));
    }
    float* bo = bet + (size_t)b * Tt * 32;
    bo[(size_t)(Tt - 1) * 32 + j] = 0.f;
    float y = lb[(size_t)(Tt - 1) * 32 + j] + 0.f;   // (logB[T-1] + beta[T-1])
    float bA = lb[(size_t)(Tt - 2) * 32 + j];
    float bB = lb[(size_t)(Tt - 3) * 32 + j];
    float bC = lb[(size_t)(Tt - 4) * 32 + j];
#pragma unroll 1
    for (int t = Tt - 2; t >= 0; --t) {
      float bcur = bA; bA = bB; bB = bC;
      if (t >= 3) bC = lb[(size_t)(t - 3) * 32 + j];
      float z[32];
#pragma unroll
      for (int i = 0; i < 32; ++i) z[i] = arow[i] + rdlane(y, i);  // A[j][i] + y_i
#pragma unroll
      for (int i = 0; i < 32; ++i) asm volatile("" : "+v"(z[i])); // force z resident
      float m = max32(z);
#pragma unroll
      for (int i = 0; i < 32; ++i) z[i] = __expf(z[i] - m);
#pragma unroll
      for (int i = 0; i < 32; ++i) asm volatile("" : "+v"(z[i])); // force e resident
      float S = npsum32(z);
      float bv = __logf(S) + m;          // beta[t][j]
      bo[(size_t)t * 32 + j] = bv;
      y = bcur + bv;                     // (logB[t] + beta[t]) for next step
    }
  }
}

// ---------------- K5: gamma = (alpha + beta) - evidence, fp32 ----------------
__global__ void k_gamma(const float* __restrict__ ws, float* __restrict__ out) {
  size_t idx = (size_t)blockIdx.x * blockDim.x + threadIdx.x;
  if (idx >= (size_t)NB * Tt * 32) return;
  int b = (int)(idx >> 17);            // T*S = 131072
  float a  = out[idx];
  float bb = ws[OFF_BET + idx];
  float e  = ws[OFF_EV + b];
  out[idx] = (a + bb) - e;
}

extern "C" void kernel_launch(void* const* d_in, const int* in_sizes, int n_in,
                              void* d_out, int out_size, void* d_ws, size_t ws_size,
                              hipStream_t stream) {
  const float* x     = (const float*)d_in[0];
  const float* means = (const float*)d_in[1];
  const float* covs  = (const float*)d_in[2];
  const float* logA  = (const float*)d_in[3];
  const float* logpi = (const float*)d_in[4];
  float* ws  = (float*)d_ws;
  float* out = (float*)d_out;

  k_chol<<<dim3(32), dim3(64), 0, stream>>>(covs, means, ws);
  k_emis<<<dim3(4096), dim3(64), 0, stream>>>(x, ws, ws + OFF_LB);
  k_fb<<<dim3(32), dim3(64), 0, stream>>>(logA, logpi, ws, out);
  k_gamma<<<dim3(8192), dim3(256), 0, stream>>>(ws, out);
}

// Round 3
// 2465.702 us; speedup vs baseline: 1.1920x; 1.1920x over previous
//
#include <hip/hip_runtime.h>
#include <math.h>

#define Tt 4096
#define NB 16

#define CLN2PI 1.8378770664093453f   // ln(2*pi)

// ws layout (float offsets)
#define OFF_W    0         // 131072  W = L^-1 per state (row-major, upper zeros)
#define OFF_D    131072    // 2048    d = W*mu
#define OFF_CST  133120    // 32      F*ln2pi + logdet  (nats)
#define OFF_EV   133152    // 16      evidence per batch (fp32 nats)
#define OFF_LB   133184    // 2097152 logB nats [b][t][s]
#define OFF_BET  2230336   // 2097152 beta  nats [b][t][s]
// total 4327488 floats = 17.3 MB

__device__ __forceinline__ float rdlane(float x, int l) {
  return __int_as_float(__builtin_amdgcn_readlane(__float_as_int(x), l));
}
// pull value from lane (addr>>2); addr in bytes
__device__ __forceinline__ float bpmf(int addr, float x) {
  return __int_as_float(__builtin_amdgcn_ds_bpermute(addr, __float_as_int(x)));
}

// ---------------- K2: per-state Cholesky, W = L^-1, d = W*mu, cst ----------------
__global__ __launch_bounds__(64) void k_chol(const float* __restrict__ covs,
                                             const float* __restrict__ means,
                                             float* __restrict__ ws) {
  __shared__ float Am[64][65];
  __shared__ float Wl[64][65];
  int s = blockIdx.x, j = threadIdx.x;
  for (int r = 0; r < 64; ++r) {
    Am[r][j] = covs[((size_t)s * 64 + r) * 64 + j];
    Wl[r][j] = 0.f;
  }
  __syncthreads();
  for (int k = 0; k < 64; ++k) {
    float diag = sqrtf(Am[k][k]);
    float col = (j > k) ? Am[j][k] / diag : 0.f;
    __syncthreads();
    if (j == k) Am[k][k] = diag;
    if (j > k)  Am[j][k] = col;
    __syncthreads();
    if (j > k) {
      for (int g = k + 1; g <= j; ++g) Am[j][g] -= col * Am[g][k];
    }
    __syncthreads();
  }
  {
    int c = j;
    Wl[c][c] = 1.0f / Am[c][c];
    for (int f = c + 1; f < 64; ++f) {
      float ssum = 0.f;
      for (int g = c; g < f; ++g) ssum += Am[f][g] * Wl[g][c];
      Wl[f][c] = -ssum / Am[f][f];
    }
  }
  __syncthreads();
  for (int r = 0; r < 64; ++r)
    ws[OFF_W + ((size_t)s * 64 + r) * 64 + j] = Wl[r][j];
  {
    float acc = 0.f;
    for (int g = 0; g < 64; ++g) acc += Wl[j][g] * means[s * 64 + g];
    ws[OFF_D + s * 64 + j] = acc;
  }
  if (j == 0) {
    float logdet = 0.f;
    for (int k = 0; k < 64; ++k) logdet += __logf(Am[k][k]);
    logdet *= 2.0f;
    ws[OFF_CST + s] = 64.0f * CLN2PI + logdet;
  }
}

// ---------------- K3: emission logB (nats) ----------------
__global__ __launch_bounds__(64) void k_emis(const float* __restrict__ x,
                                             const float* __restrict__ wsr,
                                             float* __restrict__ lb) {
  const float* W = wsr + OFF_W;
  const float* D = wsr + OFF_D;
  const float* C = wsr + OFF_CST;
  int bx = blockIdx.x;
  int sgrp = bx & 3;
  int pt = (bx >> 2) * 64 + threadIdx.x;
  const float* xr = x + (size_t)pt * 64;
  float xv[64];
#pragma unroll
  for (int c = 0; c < 16; ++c) {
    float4 q = ((const float4*)xr)[c];
    xv[4 * c + 0] = q.x; xv[4 * c + 1] = q.y;
    xv[4 * c + 2] = q.z; xv[4 * c + 3] = q.w;
  }
#pragma unroll 1
  for (int si = 0; si < 8; ++si) {
    int s = sgrp * 8 + si;
    const float* Ws = W + (size_t)s * 4096;
    const float* Ds = D + s * 64;
    float maha = 0.f;
#pragma unroll
    for (int f = 0; f < 64; ++f) {
      float z = -Ds[f];
#pragma unroll
      for (int ch = 0; ch < 4; ++ch) {
        if (ch <= (f >> 4)) {
#pragma unroll
          for (int gg = 0; gg < 16; ++gg) {
            int g = ch * 16 + gg;
            z = fmaf(Ws[f * 64 + g], xv[g], z);
          }
        }
      }
      maha = fmaf(z, z, maha);
    }
    lb[(size_t)pt * 32 + s] = -0.5f * (maha + C[s]);
  }
}

// np-pairwise-order sum of 32 (matches numpy's 8-accumulator pairwise order)
__device__ __forceinline__ float npsum32(const float* z) {
  float r[8];
#pragma unroll
  for (int k = 0; k < 8; ++k)
    r[k] = ((z[k] + z[k + 8]) + z[k + 16]) + z[k + 24];
  return ((r[0] + r[1]) + (r[2] + r[3])) + ((r[4] + r[5]) + (r[6] + r[7]));
}
// exact max of 32 (order-independent, commutative -> any tree ok)
__device__ __forceinline__ float max32(const float* z) {
  float t16[16];
#pragma unroll
  for (int k = 0; k < 16; ++k) t16[k] = fmaxf(z[k], z[k + 16]);
  float t8[8];
#pragma unroll
  for (int k = 0; k < 8; ++k) t8[k] = fmaxf(t16[k], t16[k + 8]);
  float t4[4];
#pragma unroll
  for (int k = 0; k < 4; ++k) t4[k] = fmaxf(t8[k], t8[k + 4]);
  float t2a = fmaxf(t4[0], t4[2]), t2b = fmaxf(t4[1], t4[3]);
  return fmaxf(t2a, t2b);
}
// exact max of 16 (commutative -> any tree bit-matches np's max)
__device__ __forceinline__ float max16(const float* z) {
  float t8[8];
#pragma unroll
  for (int k = 0; k < 8; ++k) t8[k] = fmaxf(z[k], z[k + 8]);
  float t4[4];
#pragma unroll
  for (int k = 0; k < 4; ++k) t4[k] = fmaxf(t8[k], t8[k + 4]);
  return fmaxf(fmaxf(t4[0], t4[2]), fmaxf(t4[1], t4[3]));
}

// ---------------- K4: forward/backward, fp32 nats, np-matched ops ----------------
// 1 wave per (batch, dir). Half-split layout: lane (h=lane>>5, j=lane&31) owns
// reduction indices i in [16h, 16h+16) for state j. All arithmetic VALUES and
// op ORDER are bit-identical to the R0 np-matched kernel; only the distribution
// across lanes changed (ds_bpermute delivers per-half a_i; the np pairwise sum
// ((e_k+e_{k+8})+e_{k+16})+e_{k+24} does its inner pair on the lower half and
// the two serial adds on the upper half after one bpermute transfer).
// This halves the add/sub/exp instruction count (exp is quarter-rate!) on a
// purely latency/issue-bound serial chain. R2 lesson: NO pins on in-loop values.
__global__ __launch_bounds__(64, 1) __attribute__((amdgpu_waves_per_eu(1)))
void k_fb(const float* __restrict__ logA,
          const float* __restrict__ logpi,
          float* __restrict__ ws,
          float* __restrict__ out) {
  const float* lbg = ws + OFF_LB;
  float* bet = ws + OFF_BET;
  float* ev  = ws + OFF_EV;
  int chain = blockIdx.x;
  int b   = chain & 15;
  int dir = chain >> 4;
  int lane = threadIdx.x;
  int j = lane & 31;
  int h = lane >> 5;
  int i0 = h << 4;                       // first reduction index this half owns
  int xaddr = (lane ^ 32) << 2;          // half-swap pull address
  int baddr = (lane | 32) << 2;          // pull-from-upper broadcast address
  const float* lb = lbg + (size_t)b * Tt * 32;

  int gaddr[16];                         // gather addresses: lane i0+k
#pragma unroll
  for (int k = 0; k < 16; ++k) {
    gaddr[k] = (i0 + k) << 2;
    asm volatile("" : "+v"(gaddr[k]));
  }

  if (dir == 0) {
    float acol[16];                      // A[i0+k][j]
#pragma unroll
    for (int k = 0; k < 16; ++k) {
      acol[k] = logA[(i0 + k) * 32 + j];
      asm volatile("" : "+v"(acol[k]));
    }
    float* ao = out + (size_t)b * Tt * 32;
    float a = logpi[j] + lb[j];          // alpha[0], valid in all lanes
    ao[j] = a;
    float bA = lb[32 + j];
    float bB = lb[64 + j];
    float bC = lb[96 + j];
#pragma unroll 1
    for (int t = 1; t < Tt; ++t) {
      float bcur = bA; bA = bB; bB = bC;
      if (t + 3 < Tt) bC = lb[(size_t)(t + 3) * 32 + j];
      float z[16];
#pragma unroll
      for (int k = 0; k < 16; ++k) z[k] = bpmf(gaddr[k], a) + acol[k]; // a_{i0+k}+A[i0+k][j]
      float mh = max16(z);
      float m = fmaxf(mh, bpmf(xaddr, mh));          // full max_i z (all lanes)
      float e[16];
#pragma unroll
      for (int k = 0; k < 16; ++k) e[k] = __expf(z[k] - m);
      float p[8];
#pragma unroll
      for (int k = 0; k < 8; ++k) p[k] = e[k] + e[k + 8];   // lower: e_k+e_{k+8}
      float r[8];
#pragma unroll
      for (int k = 0; k < 8; ++k)
        r[k] = (bpmf(xaddr, p[k]) + e[k]) + e[k + 8];       // upper: (+e_{16+k})+e_{24+k}
      float S = ((r[0] + r[1]) + (r[2] + r[3])) + ((r[4] + r[5]) + (r[6] + r[7]));
      float anew = (__logf(S) + m) + bcur;                  // valid in upper lanes
      a = bpmf(baddr, anew);                                // broadcast to all lanes
      ao[(size_t)t * 32 + j] = a;
    }
    // evidence = logsumexp(alpha[T-1]) — np-exact, identical to baseline
    float z[32];
#pragma unroll
    for (int i = 0; i < 32; ++i) z[i] = rdlane(a, i);
    float m = max32(z);
#pragma unroll
    for (int i = 0; i < 32; ++i) z[i] = __expf(z[i] - m);
    float S = npsum32(z);
    if (lane == 0) ev[b] = __logf(S) + m;
  } else {
    float arow[16];                      // A[j][i0+k]
#pragma unroll
    for (int k = 0; k < 16; ++k) {
      arow[k] = logA[j * 32 + i0 + k];
      asm volatile("" : "+v"(arow[k]));
    }
    float* bo = bet + (size_t)b * Tt * 32;
    bo[(size_t)(Tt - 1) * 32 + j] = 0.f;
    float y = lb[(size_t)(Tt - 1) * 32 + j] + 0.f;   // (logB[T-1] + beta[T-1])
    float bA = lb[(size_t)(Tt - 2) * 32 + j];
    float bB = lb[(size_t)(Tt - 3) * 32 + j];
    float bC = lb[(size_t)(Tt - 4) * 32 + j];
#pragma unroll 1
    for (int t = Tt - 2; t >= 0; --t) {
      float bcur = bA; bA = bB; bB = bC;
      if (t >= 3) bC = lb[(size_t)(t - 3) * 32 + j];
      float z[16];
#pragma unroll
      for (int k = 0; k < 16; ++k) z[k] = arow[k] + bpmf(gaddr[k], y); // A[j][i]+y_i
      float mh = max16(z);
      float m = fmaxf(mh, bpmf(xaddr, mh));
      float e[16];
#pragma unroll
      for (int k = 0; k < 16; ++k) e[k] = __expf(z[k] - m);
      float p[8];
#pragma unroll
      for (int k = 0; k < 8; ++k) p[k] = e[k] + e[k + 8];
      float r[8];
#pragma unroll
      for (int k = 0; k < 8; ++k)
        r[k] = (bpmf(xaddr, p[k]) + e[k]) + e[k + 8];
      float S = ((r[0] + r[1]) + (r[2] + r[3])) + ((r[4] + r[5]) + (r[6] + r[7]));
      float bvu = __logf(S) + m;                            // valid in upper lanes
      float bv = bpmf(baddr, bvu);                          // broadcast
      bo[(size_t)t * 32 + j] = bv;
      y = bcur + bv;
    }
  }
}

// ---------------- K5: gamma = (alpha + beta) - evidence, fp32 ----------------
__global__ void k_gamma(const float* __restrict__ ws, float* __restrict__ out) {
  size_t idx = (size_t)blockIdx.x * blockDim.x + threadIdx.x;
  if (idx >= (size_t)NB * Tt * 32) return;
  int b = (int)(idx >> 17);            // T*S = 131072
  float a  = out[idx];
  float bb = ws[OFF_BET + idx];
  float e  = ws[OFF_EV + b];
  out[idx] = (a + bb) - e;
}

extern "C" void kernel_launch(void* const* d_in, const int* in_sizes, int n_in,
                              void* d_out, int out_size, void* d_ws, size_t ws_size,
                              hipStream_t stream) {
  const float* x     = (const float*)d_in[0];
  const float* means = (const float*)d_in[1];
  const float* covs  = (const float*)d_in[2];
  const float* logA  = (const float*)d_in[3];
  const float* logpi = (const float*)d_in[4];
  float* ws  = (float*)d_ws;
  float* out = (float*)d_out;

  k_chol<<<dim3(32), dim3(64), 0, stream>>>(covs, means, ws);
  k_emis<<<dim3(4096), dim3(64), 0, stream>>>(x, ws, ws + OFF_LB);
  k_fb<<<dim3(32), dim3(64), 0, stream>>>(logA, logpi, ws, out);
  k_gamma<<<dim3(8192), dim3(256), 0, stream>>>(ws, out);
}

// Round 6
// 2221.052 us; speedup vs baseline: 1.3233x; 1.1102x over previous
//
#include <hip/hip_runtime.h>
#include <math.h>

#define Tt 4096
#define NB 16

#define CLN2PI 1.8378770664093453f   // ln(2*pi)

// ws layout (float offsets)
#define OFF_W    0         // 131072  W = L^-1 per state (row-major, upper zeros)
#define OFF_D    131072    // 2048    d = W*mu
#define OFF_CST  133120    // 32      F*ln2pi + logdet  (nats)
#define OFF_EV   133152    // 16      evidence per batch (fp32 nats)
#define OFF_LB   133184    // 2097152 logB nats [b][t][s]
#define OFF_BET  2230336   // 2097152 beta  nats [b][t][s]
// total 4327488 floats = 17.3 MB

__device__ __forceinline__ float rdlane(float x, int l) {
  return __int_as_float(__builtin_amdgcn_readlane(__float_as_int(x), l));
}

// Per-lane cross-half exchange via v_permlane32_swap (VALU, ~10cy — vs
// ds_bpermute's ~120cy LDS round-trip, 2x on the serial chain in R3).
// With old=src=v the swap returns: lo = v[lane&31] (lower partner, same j),
// hi = v[32|(lane&31)] (upper partner, same j) — in ALL lanes. fmax/add of
// (lo,hi) is therefore per-j-correct and bit-identical across halves.
// R4 lesson: inline asm with two identical tied operands got coalesced into
// one register -> garbage. The intrinsic models both results -> safe.
// R5 lesson: rdlane(x, fixed_lane) broadcasts ONE state's value — only valid
// for wave-uniform x. Per-column reduces need the partner exchange below.
typedef unsigned int u32x2 __attribute__((ext_vector_type(2)));
__device__ __forceinline__ void xhalf(float v, float& lo, float& hi) {
  u32x2 r = __builtin_amdgcn_permlane32_swap(__float_as_uint(v), __float_as_uint(v),
                                             false, false);
  lo = __uint_as_float(r.x);
  hi = __uint_as_float(r.y);
}

// ---------------- K2: per-state Cholesky, W = L^-1, d = W*mu, cst ----------------
__global__ __launch_bounds__(64) void k_chol(const float* __restrict__ covs,
                                             const float* __restrict__ means,
                                             float* __restrict__ ws) {
  __shared__ float Am[64][65];
  __shared__ float Wl[64][65];
  int s = blockIdx.x, j = threadIdx.x;
  for (int r = 0; r < 64; ++r) {
    Am[r][j] = covs[((size_t)s * 64 + r) * 64 + j];
    Wl[r][j] = 0.f;
  }
  __syncthreads();
  for (int k = 0; k < 64; ++k) {
    float diag = sqrtf(Am[k][k]);
    float col = (j > k) ? Am[j][k] / diag : 0.f;
    __syncthreads();
    if (j == k) Am[k][k] = diag;
    if (j > k)  Am[j][k] = col;
    __syncthreads();
    if (j > k) {
      for (int g = k + 1; g <= j; ++g) Am[j][g] -= col * Am[g][k];
    }
    __syncthreads();
  }
  {
    int c = j;
    Wl[c][c] = 1.0f / Am[c][c];
    for (int f = c + 1; f < 64; ++f) {
      float ssum = 0.f;
      for (int g = c; g < f; ++g) ssum += Am[f][g] * Wl[g][c];
      Wl[f][c] = -ssum / Am[f][f];
    }
  }
  __syncthreads();
  for (int r = 0; r < 64; ++r)
    ws[OFF_W + ((size_t)s * 64 + r) * 64 + j] = Wl[r][j];
  {
    float acc = 0.f;
    for (int g = 0; g < 64; ++g) acc += Wl[j][g] * means[s * 64 + g];
    ws[OFF_D + s * 64 + j] = acc;
  }
  if (j == 0) {
    float logdet = 0.f;
    for (int k = 0; k < 64; ++k) logdet += __logf(Am[k][k]);
    logdet *= 2.0f;
    ws[OFF_CST + s] = 64.0f * CLN2PI + logdet;
  }
}

// ---------------- K3: emission logB (nats) ----------------
__global__ __launch_bounds__(64) void k_emis(const float* __restrict__ x,
                                             const float* __restrict__ wsr,
                                             float* __restrict__ lb) {
  const float* W = wsr + OFF_W;
  const float* D = wsr + OFF_D;
  const float* C = wsr + OFF_CST;
  int bx = blockIdx.x;
  int sgrp = bx & 3;
  int pt = (bx >> 2) * 64 + threadIdx.x;
  const float* xr = x + (size_t)pt * 64;
  float xv[64];
#pragma unroll
  for (int c = 0; c < 16; ++c) {
    float4 q = ((const float4*)xr)[c];
    xv[4 * c + 0] = q.x; xv[4 * c + 1] = q.y;
    xv[4 * c + 2] = q.z; xv[4 * c + 3] = q.w;
  }
#pragma unroll 1
  for (int si = 0; si < 8; ++si) {
    int s = sgrp * 8 + si;
    const float* Ws = W + (size_t)s * 4096;
    const float* Ds = D + s * 64;
    float maha = 0.f;
#pragma unroll
    for (int f = 0; f < 64; ++f) {
      float z = -Ds[f];
#pragma unroll
      for (int ch = 0; ch < 4; ++ch) {
        if (ch <= (f >> 4)) {
#pragma unroll
          for (int gg = 0; gg < 16; ++gg) {
            int g = ch * 16 + gg;
            z = fmaf(Ws[f * 64 + g], xv[g], z);
          }
        }
      }
      maha = fmaf(z, z, maha);
    }
    lb[(size_t)pt * 32 + s] = -0.5f * (maha + C[s]);
  }
}

// np-pairwise-order sum of 32 (evidence only)
__device__ __forceinline__ float npsum32(const float* z) {
  float r[8];
#pragma unroll
  for (int k = 0; k < 8; ++k)
    r[k] = ((z[k] + z[k + 8]) + z[k + 16]) + z[k + 24];
  return ((r[0] + r[1]) + (r[2] + r[3])) + ((r[4] + r[5]) + (r[6] + r[7]));
}
// exact max of 32 (order-independent, commutative -> any tree ok)
__device__ __forceinline__ float max32(const float* z) {
  float t16[16];
#pragma unroll
  for (int k = 0; k < 16; ++k) t16[k] = fmaxf(z[k], z[k + 16]);
  float t8[8];
#pragma unroll
  for (int k = 0; k < 8; ++k) t8[k] = fmaxf(t16[k], t16[k + 8]);
  float t4[4];
#pragma unroll
  for (int k = 0; k < 4; ++k) t4[k] = fmaxf(t8[k], t8[k + 4]);
  float t2a = fmaxf(t4[0], t4[2]), t2b = fmaxf(t4[1], t4[3]);
  return fmaxf(t2a, t2b);
}
// exact max of 16 (commutative -> any tree yields THE max, bit-exact)
__device__ __forceinline__ float max16(const float* z) {
  float t8[8];
#pragma unroll
  for (int k = 0; k < 8; ++k) t8[k] = fmaxf(z[k], z[k + 8]);
  float t4[4];
#pragma unroll
  for (int k = 0; k < 4; ++k) t4[k] = fmaxf(t8[k], t8[k + 4]);
  return fmaxf(fmaxf(t4[0], t4[2]), fmaxf(t4[1], t4[3]));
}
// tree sum of 16 (order differs from np pairwise; perturbs logS ~1e-7 -> safe:
// the big-magnitude adds (z, final a-updates) stay np-ordered, which is what
// the R1 failure showed must be preserved)
__device__ __forceinline__ float sum16(const float* e) {
  float t8[8];
#pragma unroll
  for (int k = 0; k < 8; ++k) t8[k] = e[k] + e[k + 8];
  float t4[4];
#pragma unroll
  for (int k = 0; k < 4; ++k) t4[k] = t8[k] + t8[k + 4];
  return (t4[0] + t4[2]) + (t4[1] + t4[3]);
}

// ---------------- K4: forward/backward, fp32 nats ----------------
// 1 wave per (batch, dir). Half-split: lane (h=lane>>5, j=lane&31) owns
// reduction indices i in [16h,16h+16) for state j -> 16 exps/step not 32
// (exp is quarter-rate, the biggest single issue cost).
// Gather of the a/y vector: 32 v_readlane -> SGPRs (valid: a is identical in
// both halves, so lanes 0..31 hold the full vector). Cross-half combine of
// the per-column partial max/sum: permlane32_swap partner exchange (xhalf).
__global__ __launch_bounds__(64, 1) __attribute__((amdgpu_waves_per_eu(1)))
void k_fb(const float* __restrict__ logA,
          const float* __restrict__ logpi,
          float* __restrict__ ws,
          float* __restrict__ out) {
  const float* lbg = ws + OFF_LB;
  float* bet = ws + OFF_BET;
  float* ev  = ws + OFF_EV;
  int chain = blockIdx.x;
  int b   = chain & 15;
  int dir = chain >> 4;
  int lane = threadIdx.x;
  int j = lane & 31;
  int h = lane >> 5;
  int i0 = h << 4;                       // first reduction index this half owns
  const float* lb = lbg + (size_t)b * Tt * 32;

  if (dir == 0) {
    float acol[16];                      // A[i0+k][j]
#pragma unroll
    for (int k = 0; k < 16; ++k) {
      acol[k] = logA[(i0 + k) * 32 + j];
      asm volatile("" : "+v"(acol[k]));
    }
    float* ao = out + (size_t)b * Tt * 32;
    float a = logpi[j] + lb[j];          // alpha[0], identical in both halves
    ao[j] = a;
    float bA = lb[32 + j];
    float bB = lb[64 + j];
    float bC = lb[96 + j];
#pragma unroll 1
    for (int t = 1; t < Tt; ++t) {
      float bcur = bA; bA = bB; bB = bC;
      if (t + 3 < Tt) bC = lb[(size_t)(t + 3) * 32 + j];
      float sa[32];                      // uniform (SGPR) gather of a-vector
#pragma unroll
      for (int i = 0; i < 32; ++i) sa[i] = rdlane(a, i);
      float z[16];
      if (h == 0) {
#pragma unroll
        for (int k = 0; k < 16; ++k) z[k] = sa[k] + acol[k];      // a_i + A[i][j]
      } else {
#pragma unroll
        for (int k = 0; k < 16; ++k) z[k] = sa[16 + k] + acol[k];
      }
      float mh = max16(z);               // per-(half,j) exact max
      float mlo, mhi;
      xhalf(mh, mlo, mhi);               // partner exchange (same j)
      float m = fmaxf(mlo, mhi);         // full max_i, same bits all lanes
      float e[16];
#pragma unroll
      for (int k = 0; k < 16; ++k) e[k] = __expf(z[k] - m);  // z-m exact
      float sh = sum16(e);               // per-(half,j) tree sum
      float slo, shi;
      xhalf(sh, slo, shi);
      float S = slo + shi;               // full sum, same bits all lanes
      a = (__logf(S) + m) + bcur;        // np-ordered final adds
      ao[(size_t)t * 32 + j] = a;        // halves write same value -> safe
    }
    // evidence = logsumexp(alpha[T-1]) — np-exact, identical to baseline
    float z[32];
#pragma unroll
    for (int i = 0; i < 32; ++i) z[i] = rdlane(a, i);
    float m = max32(z);
#pragma unroll
    for (int i = 0; i < 32; ++i) z[i] = __expf(z[i] - m);
    float S = npsum32(z);
    if (lane == 0) ev[b] = __logf(S) + m;
  } else {
    float arow[16];                      // A[j][i0+k]
#pragma unroll
    for (int k = 0; k < 16; ++k) {
      arow[k] = logA[j * 32 + i0 + k];
      asm volatile("" : "+v"(arow[k]));
    }
    float* bo = bet + (size_t)b * Tt * 32;
    bo[(size_t)(Tt - 1) * 32 + j] = 0.f;
    float y = lb[(size_t)(Tt - 1) * 32 + j] + 0.f;   // (logB[T-1] + beta[T-1])
    float bA = lb[(size_t)(Tt - 2) * 32 + j];
    float bB = lb[(size_t)(Tt - 3) * 32 + j];
    float bC = lb[(size_t)(Tt - 4) * 32 + j];
#pragma unroll 1
    for (int t = Tt - 2; t >= 0; --t) {
      float bcur = bA; bA = bB; bB = bC;
      if (t >= 3) bC = lb[(size_t)(t - 3) * 32 + j];
      float sy[32];                      // uniform (SGPR) gather of y-vector
#pragma unroll
      for (int i = 0; i < 32; ++i) sy[i] = rdlane(y, i);
      float z[16];
      if (h == 0) {
#pragma unroll
        for (int k = 0; k < 16; ++k) z[k] = arow[k] + sy[k];      // A[j][i]+y_i
      } else {
#pragma unroll
        for (int k = 0; k < 16; ++k) z[k] = arow[k] + sy[16 + k];
      }
      float mh = max16(z);
      float mlo, mhi;
      xhalf(mh, mlo, mhi);
      float m = fmaxf(mlo, mhi);
      float e[16];
#pragma unroll
      for (int k = 0; k < 16; ++k) e[k] = __expf(z[k] - m);
      float sh = sum16(e);
      float slo, shi;
      xhalf(sh, slo, shi);
      float S = slo + shi;
      float bv = __logf(S) + m;          // beta[t][j], same bits both halves
      bo[(size_t)t * 32 + j] = bv;
      y = bcur + bv;                     // (logB[t] + beta[t]) for next step
    }
  }
}

// ---------------- K5: gamma = (alpha + beta) - evidence, fp32 ----------------
__global__ void k_gamma(const float* __restrict__ ws, float* __restrict__ out) {
  size_t idx = (size_t)blockIdx.x * blockDim.x + threadIdx.x;
  if (idx >= (size_t)NB * Tt * 32) return;
  int b = (int)(idx >> 17);            // T*S = 131072
  float a  = out[idx];
  float bb = ws[OFF_BET + idx];
  float e  = ws[OFF_EV + b];
  out[idx] = (a + bb) - e;
}

extern "C" void kernel_launch(void* const* d_in, const int* in_sizes, int n_in,
                              void* d_out, int out_size, void* d_ws, size_t ws_size,
                              hipStream_t stream) {
  const float* x     = (const float*)d_in[0];
  const float* means = (const float*)d_in[1];
  const float* covs  = (const float*)d_in[2];
  const float* logA  = (const float*)d_in[3];
  const float* logpi = (const float*)d_in[4];
  float* ws  = (float*)d_ws;
  float* out = (float*)d_out;

  k_chol<<<dim3(32), dim3(64), 0, stream>>>(covs, means, ws);
  k_emis<<<dim3(4096), dim3(64), 0, stream>>>(x, ws, ws + OFF_LB);
  k_fb<<<dim3(32), dim3(64), 0, stream>>>(logA, logpi, ws, out);
  k_gamma<<<dim3(8192), dim3(256), 0, stream>>>(ws, out);
}